// Round 11
// baseline (379.207 us; speedup 1.0000x reference)
//
#include <hip/hip_runtime.h>

#define BATCH 16
#define CCH 512
#define LEN 4096
#define LPAD 4098

typedef unsigned short u16;
typedef __bf16 bf16x8 __attribute__((ext_vector_type(8)));
typedef float f32x4 __attribute__((ext_vector_type(4)));
typedef u16 u16x8 __attribute__((ext_vector_type(8)));
typedef u16 u16x4 __attribute__((ext_vector_type(4)));

__device__ __forceinline__ u16 f2bf(float f) {
    unsigned u = __float_as_uint(f);
    u = (u + 0x7fffu + ((u >> 16) & 1u)) >> 16;
    return (u16)u;
}
__device__ __forceinline__ float bf2f(u16 v) {
    return __uint_as_float(((unsigned)v) << 16);
}
__device__ __forceinline__ float silu_f(float v) {
    return v / (1.f + __expf(-v));
}
__device__ __forceinline__ void async16(const u16* g, u16* l) {
    __builtin_amdgcn_global_load_lds(
        (const __attribute__((address_space(1))) unsigned int*)g,
        (__attribute__((address_space(3))) unsigned int*)l, 16, 0, 0);
}

#define SBAR() __builtin_amdgcn_sched_barrier(0)
#define HWBAR() { SBAR(); __builtin_amdgcn_s_barrier(); SBAR(); }
#define WAIT_LGKM0() { asm volatile("s_waitcnt lgkmcnt(0)" ::: "memory"); SBAR(); }
#define WAIT_VM(n) { asm volatile("s_waitcnt vmcnt(" #n ")" ::: "memory"); SBAR(); }

// ---------------------------------------------------------------------------
__global__ __launch_bounds__(256)
void absmean_partial(const float* __restrict__ w1, const float* __restrict__ w2,
                     float* __restrict__ part) {
    const int tid = threadIdx.x;
    const int base = blockIdx.x * 3072;
    float s1 = 0.f, s2 = 0.f;
    for (int i = tid; i < 3072; i += 256) {
        s1 += fabsf(w1[base + i]);
        s2 += fabsf(w2[base + i]);
    }
    __shared__ float r1[256], r2[256];
    r1[tid] = s1; r2[tid] = s2;
    __syncthreads();
    for (int off = 128; off > 0; off >>= 1) {
        if (tid < off) { r1[tid] += r1[tid + off]; r2[tid] += r2[tid + off]; }
        __syncthreads();
    }
    if (tid == 0) { part[blockIdx.x] = r1[0]; part[256 + blockIdx.x] = r2[0]; }
}

__global__ __launch_bounds__(256)
void finalize_scale(const float* __restrict__ part, float* __restrict__ sv) {
    const int tid = threadIdx.x;
    __shared__ float r1[256], r2[256];
    r1[tid] = part[tid]; r2[tid] = part[256 + tid];
    __syncthreads();
    for (int off = 128; off > 0; off >>= 1) {
        if (tid < off) { r1[tid] += r1[tid + off]; r2[tid] += r2[tid + off]; }
        __syncthreads();
    }
    if (tid == 0) {
        sv[0] = fmaxf(r1[0] * (1.f / 786432.f), 1e-5f);
        sv[1] = fmaxf(r2[0] * (1.f / 786432.f), 1e-5f);
    }
}

// ---------------------------------------------------------------------------
__global__ __launch_bounds__(256)
void quantize_both(const float* __restrict__ w1, const float* __restrict__ w2,
                   const float* __restrict__ sv,
                   u16* __restrict__ wq1, u16* __restrict__ wq2) {
    const int idx = blockIdx.x * 256 + threadIdx.x;   // [0, 786432)
    const float s1 = sv[0], s2 = sv[1];
    const int o   = idx / 1536;
    const int rem = idx - o * 1536;
    const int i   = rem / 3;
    const int k   = rem - i * 3;
    const int dst = k * (CCH * CCH) + o * CCH + i;
    float q1 = fmaxf(-1.f, fminf(1.f, rintf(w1[idx] / s1)));
    float q2 = fmaxf(-1.f, fminf(1.f, rintf(w2[idx] / s2)));
    wq1[dst] = f2bf(q1);
    wq2[dst] = f2bf(q2);
}

__global__ __launch_bounds__(256)
void zero_pads(u16* __restrict__ h, u16* __restrict__ h1) {
    const int idx = blockIdx.x * 256 + threadIdx.x;   // [0, 16384)
    const int b = idx >> 10;
    const int r = (idx >> 9) & 1;
    const int i = idx & 511;
    const size_t off = ((size_t)b * LPAD + (r ? (LPAD - 1) : 0)) * CCH + i;
    h[off] = 0;
    h1[off] = 0;
}

// ---------------------------------------------------------------------------
__global__ __launch_bounds__(256)
void rms_silu_transpose(const float* __restrict__ x, const float* __restrict__ g,
                        u16* __restrict__ h_t) {
    __shared__ u16   xt[CCH][33];
    __shared__ float red[8][32];
    __shared__ float rinv[32];
    const int tid = threadIdx.x;
    const int bb  = blockIdx.x >> 7;
    const int l0  = (blockIdx.x & 127) << 5;

    const size_t xbase = (size_t)bb * CCH * LEN + l0;
    {
        const int i_hi = tid >> 3;
        const int l4   = (tid & 7) << 2;
        #pragma unroll
        for (int it = 0; it < 16; ++it) {
            const int i = it * 32 + i_hi;
            const float4 v = *(const float4*)&x[xbase + (size_t)i * LEN + l4];
            xt[i][l4 + 0] = f2bf(v.x);
            xt[i][l4 + 1] = f2bf(v.y);
            xt[i][l4 + 2] = f2bf(v.z);
            xt[i][l4 + 3] = f2bf(v.w);
        }
    }
    __syncthreads();
    {
        const int l = tid & 31, seg = tid >> 5;
        const int ibeg = seg * 64;
        float ss = 0.f;
        #pragma unroll 8
        for (int i = ibeg; i < ibeg + 64; ++i) {
            const float v = bf2f(xt[i][l]);
            ss += v * v;
        }
        red[seg][l] = ss;
    }
    __syncthreads();
    if (tid < 32) {
        float tot = 0.f;
        #pragma unroll
        for (int k2 = 0; k2 < 8; ++k2) tot += red[k2][tid];
        rinv[tid] = rsqrtf(tot * (1.f / 512.f) + 1e-6f);
    }
    __syncthreads();
    {
        const int l  = tid >> 3;
        const int i0 = (tid & 7) << 6;
        const float ri = rinv[l];
        const size_t ob = ((size_t)bb * LPAD + l0 + l + 1) * CCH + i0;
        for (int ii = 0; ii < 64; ii += 8) {
            u16x8 ov;
            #pragma unroll
            for (int jj = 0; jj < 8; ++jj) {
                const int i = i0 + ii + jj;
                float v = bf2f(xt[i][l]) * ri * g[i];
                ov[jj] = f2bf(silu_f(v));
            }
            *(u16x8*)&h_t[ob + ii] = ov;
        }
    }
}

// ---------------------------------------------------------------------------
// Conv-as-GEMM, R6 structure (proven: 0 bank conflicts, best time) with a
// de-serialized step body: NO setprio (it fenced the scheduler), all 16
// ds_read_b128 issued before the 32 MFMAs (compiler inserts fine-grained
// lgkmcnt(8)/(0) -> kk0 MFMAs overlap kk1 read returns), t-loop unrolled x2
// so LDS bases are compile-time constants.
// 256x256 tile, 1024 threads = 16 waves (4M x 4N), per-wave 64x64
// (4x4 16x16x32 frags, acc=64).  BK=64, double-buffered 128 KiB LDS,
// one barrier per K-step.  T1 XCD chunking, T2 swizzle.
template<int EPI>
__global__ __launch_bounds__(1024)
void conv_gemm11(const u16* __restrict__ Bsrc, const u16* __restrict__ Wq,
                 const float* __restrict__ sptr, const float* __restrict__ bias,
                 const float* __restrict__ resid, u16* __restrict__ outb,
                 float* __restrict__ outf) {
    extern __shared__ u16 lds[];          // 65536 u16 = 128 KiB
    const int tid  = threadIdx.x;
    const int lane = tid & 63;
    const int wave = tid >> 6;
    const int wm = wave >> 2;             // 0..3  (M quarter)
    const int wn = wave & 3;              // 0..3  (N quarter)

    // T1: bijective XCD chunking (512 = 8 x 64); mt-pairs share a B-panel.
    const int wgid = (blockIdx.x & 7) * 64 + (blockIdx.x >> 3);
    const int mt = wgid & 1;
    const int nt = wgid >> 1;
    const int o0 = mt << 8;
    const int bb = nt >> 4;
    const int l0 = (nt & 15) << 8;

    // staging (R6-proven): row = j*128 + (tid>>3), pre-swizzled source col
    const int sr  = tid >> 3;                              // 0..127
    const int scu = ((tid & 7) << 3) ^ ((sr & 7) << 3);
    const int sdst = tid << 3;

    const u16* aSrcBase = Wq + (size_t)o0 * CCH + scu;
    const u16* bSrcBase = Bsrc + ((size_t)bb * LPAD + l0) * CCH + scu;

    auto stage_full = [&](int pb, int ks2, int i02) {
        #pragma unroll
        for (int j = 0; j < 2; ++j) {
            const int r = j * 128 + sr;
            async16(aSrcBase + ks2 * (CCH * CCH) + r * CCH + i02,
                    &lds[pb * 32768 + j * 8192 + sdst]);
            async16(bSrcBase + (size_t)(r + ks2) * CCH + i02,
                    &lds[pb * 32768 + 16384 + j * 8192 + sdst]);
        }
    };

    // ds_read geometry (R6-proven swizzle): kk=0 cols 0..31, kk=1 cols 32..63.
    const int swz = (lane & 7) << 3;
    const int c0 = ((lane >> 4) << 3) ^ swz;
    const int c1 = (((lane >> 4) << 3) + 32) ^ swz;
    const int aB = wm * 4096 + (lane & 15) * 64;           // A region base (u16)
    const int bB = 16384 + wn * 4096 + (lane & 15) * 64;   // B region base

    f32x4 acc[4][4];
    #pragma unroll
    for (int m = 0; m < 4; ++m)
        #pragma unroll
        for (int n = 0; n < 4; ++n)
            acc[m][n] = (f32x4){0.f, 0.f, 0.f, 0.f};

    stage_full(0, 0, 0);
    WAIT_VM(0);
    HWBAR();

    // one K-step on buffer CB (compile-time), staging next into CB^1
    int ks = 0, i0 = 0;
    auto step = [&](int t, int cbase, int obase) {
        int ksn = ks + 1, i0n = i0;
        if (ksn == 3) { ksn = 0; i0n += 64; }
        if (t < 23) stage_full(obase ? 1 : 0, ksn, i0n);
        // issue ALL 16 reads first (kk0 then kk1); no setprio anywhere
        bf16x8 a0[4], b0[4], a1[4], b1[4];
        #pragma unroll
        for (int m = 0; m < 4; ++m)
            a0[m] = *(const bf16x8*)&lds[cbase + aB + m * 1024 + c0];
        #pragma unroll
        for (int n = 0; n < 4; ++n)
            b0[n] = *(const bf16x8*)&lds[cbase + bB + n * 1024 + c0];
        #pragma unroll
        for (int m = 0; m < 4; ++m)
            a1[m] = *(const bf16x8*)&lds[cbase + aB + m * 1024 + c1];
        #pragma unroll
        for (int n = 0; n < 4; ++n)
            b1[n] = *(const bf16x8*)&lds[cbase + bB + n * 1024 + c1];
        #pragma unroll
        for (int m = 0; m < 4; ++m)
            #pragma unroll
            for (int n = 0; n < 4; ++n)
                acc[m][n] = __builtin_amdgcn_mfma_f32_16x16x32_bf16(
                    a0[m], b0[n], acc[m][n], 0, 0, 0);
        #pragma unroll
        for (int m = 0; m < 4; ++m)
            #pragma unroll
            for (int n = 0; n < 4; ++n)
                acc[m][n] = __builtin_amdgcn_mfma_f32_16x16x32_bf16(
                    a1[m], b1[n], acc[m][n], 0, 0, 0);
        WAIT_LGKM0();                  // buf reads retired (WAR safety)
        if (t < 23) { WAIT_VM(0); }    // next tile landed
        HWBAR();
        ks = ksn; i0 = i0n;
    };

    #pragma unroll 2
    for (int t = 0; t < 24; ++t) {
        if ((t & 1) == 0) step(t, 0, 1);
        else              step(t, 32768, 0);
    }

    // epilogue (R6-proven)
    const float sc = sptr[0];

    if (EPI == 1) {
        #pragma unroll
        for (int m = 0; m < 4; ++m) {
            const int o_loc = wm * 64 + m * 16 + ((lane >> 4) << 2);
            const int ob = o0 + o_loc;
            const float b0 = bias[ob + 0], b1 = bias[ob + 1];
            const float b2 = bias[ob + 2], b3 = bias[ob + 3];
            #pragma unroll
            for (int n = 0; n < 4; ++n) {
                const int l_loc = wn * 64 + n * 16 + (lane & 15);
                const f32x4 a = acc[m][n];
                u16x4 ov;
                ov[0] = f2bf(silu_f(sc * a[0] + b0));
                ov[1] = f2bf(silu_f(sc * a[1] + b1));
                ov[2] = f2bf(silu_f(sc * a[2] + b2));
                ov[3] = f2bf(silu_f(sc * a[3] + b3));
                char* p = (char*)lds + l_loc * 512 +
                          (((unsigned)(o_loc << 1)) ^ ((l_loc & 7) << 4));
                *(u16x4*)p = ov;
            }
        }
        __syncthreads();
        const int l_r = tid >> 2;            // 0..255
        const int oq  = (tid & 3) << 3;      // u16: 0,8,16,24
        u16* gdst = outb + ((size_t)bb * LPAD + l0 + l_r + 1) * CCH + o0 + oq;
        char* srp = (char*)lds + l_r * 512;
        const int swz2 = (l_r & 7) << 4;
        #pragma unroll
        for (int c = 0; c < 8; ++c) {
            const uint4 v = *(const uint4*)(srp + (((oq << 1) + c * 64) ^ swz2));
            *(uint4*)(gdst + c * 32) = v;
        }
    } else {
        const int lbase = l0 + wn * 64 + (lane & 15);
        const int obase = o0 + wm * 64 + ((lane >> 4) << 2);
        #pragma unroll
        for (int m = 0; m < 4; ++m) {
            const int ob = obase + m * 16;
            #pragma unroll
            for (int n = 0; n < 4; ++n) {
                const int l = lbase + n * 16;
                const f32x4 a = acc[m][n];
                #pragma unroll
                for (int jj = 0; jj < 4; ++jj) {
                    const size_t idx = ((size_t)bb * CCH + (ob + jj)) * LEN + l;
                    outf[idx] = sc * a[jj] + bias[ob + jj] + resid[idx];
                }
            }
        }
    }
}

// ---------------------------------------------------------------------------
extern "C" void kernel_launch(void* const* d_in, const int* in_sizes, int n_in,
                              void* d_out, int out_size, void* d_ws, size_t ws_size,
                              hipStream_t stream) {
    const float* x  = (const float*)d_in[0];
    const float* w1 = (const float*)d_in[1];
    const float* b1 = (const float*)d_in[2];
    const float* w2 = (const float*)d_in[3];
    const float* b2 = (const float*)d_in[4];
    const float* g  = (const float*)d_in[5];
    float* out = (float*)d_out;

    char* ws = (char*)d_ws;
    float* sv   = (float*)ws;
    float* part = (float*)(ws + 256);
    u16* wq1   = (u16*)(ws + 4096);
    u16* wq2   = (u16*)(ws + 4096 + 1572864);
    u16* h_t   = (u16*)(ws + 4096 + 2 * 1572864);                 // [16][4098][512] bf16
    u16* h1_t  = (u16*)(ws + 4096 + 2 * 1572864 + 67141632);      // [16][4098][512] bf16

    hipFuncSetAttribute((const void*)conv_gemm11<1>,
                        hipFuncAttributeMaxDynamicSharedMemorySize, 131072);
    hipFuncSetAttribute((const void*)conv_gemm11<2>,
                        hipFuncAttributeMaxDynamicSharedMemorySize, 131072);

    absmean_partial<<<dim3(256), dim3(256), 0, stream>>>(w1, w2, part);
    finalize_scale<<<dim3(1), dim3(256), 0, stream>>>(part, sv);
    quantize_both<<<dim3(3072), dim3(256), 0, stream>>>(w1, w2, sv, wq1, wq2);
    zero_pads<<<dim3(64), dim3(256), 0, stream>>>(h_t, h1_t);
    rms_silu_transpose<<<dim3(2048), dim3(256), 0, stream>>>(x, g, h_t);
    conv_gemm11<1><<<dim3(512), dim3(1024), 131072, stream>>>(h_t, wq1, sv, b1,
                                                              nullptr, h1_t, nullptr);
    conv_gemm11<2><<<dim3(512), dim3(1024), 131072, stream>>>(h1_t, wq2, sv + 1, b2,
                                                              x, nullptr, out);
}

// Round 12
// 343.280 us; speedup vs baseline: 1.1047x; 1.1047x over previous
//
#include <hip/hip_runtime.h>

#define BATCH 16
#define CCH 512
#define LEN 4096
#define LPAD 4098

typedef unsigned short u16;
typedef __bf16 bf16x8 __attribute__((ext_vector_type(8)));
typedef float f32x4 __attribute__((ext_vector_type(4)));
typedef u16 u16x8 __attribute__((ext_vector_type(8)));
typedef u16 u16x4 __attribute__((ext_vector_type(4)));

__device__ __forceinline__ u16 f2bf(float f) {
    unsigned u = __float_as_uint(f);
    u = (u + 0x7fffu + ((u >> 16) & 1u)) >> 16;
    return (u16)u;
}
__device__ __forceinline__ float bf2f(u16 v) {
    return __uint_as_float(((unsigned)v) << 16);
}
__device__ __forceinline__ float silu_f(float v) {
    return v / (1.f + __expf(-v));
}
__device__ __forceinline__ void async16(const u16* g, u16* l) {
    __builtin_amdgcn_global_load_lds(
        (const __attribute__((address_space(1))) unsigned int*)g,
        (__attribute__((address_space(3))) unsigned int*)l, 16, 0, 0);
}

#define SBAR() __builtin_amdgcn_sched_barrier(0)
#define HWBAR() { SBAR(); __builtin_amdgcn_s_barrier(); SBAR(); }
#define WAIT_LGKM0() { asm volatile("s_waitcnt lgkmcnt(0)" ::: "memory"); SBAR(); }
#define WAIT_VM(n) { asm volatile("s_waitcnt vmcnt(" #n ")" ::: "memory"); SBAR(); }

// ---------------------------------------------------------------------------
__global__ __launch_bounds__(256)
void absmean_partial(const float* __restrict__ w1, const float* __restrict__ w2,
                     float* __restrict__ part) {
    const int tid = threadIdx.x;
    const int base = blockIdx.x * 3072;
    float s1 = 0.f, s2 = 0.f;
    for (int i = tid; i < 3072; i += 256) {
        s1 += fabsf(w1[base + i]);
        s2 += fabsf(w2[base + i]);
    }
    __shared__ float r1[256], r2[256];
    r1[tid] = s1; r2[tid] = s2;
    __syncthreads();
    for (int off = 128; off > 0; off >>= 1) {
        if (tid < off) { r1[tid] += r1[tid + off]; r2[tid] += r2[tid + off]; }
        __syncthreads();
    }
    if (tid == 0) { part[blockIdx.x] = r1[0]; part[256 + blockIdx.x] = r2[0]; }
}

__global__ __launch_bounds__(256)
void finalize_scale(const float* __restrict__ part, float* __restrict__ sv) {
    const int tid = threadIdx.x;
    __shared__ float r1[256], r2[256];
    r1[tid] = part[tid]; r2[tid] = part[256 + tid];
    __syncthreads();
    for (int off = 128; off > 0; off >>= 1) {
        if (tid < off) { r1[tid] += r1[tid + off]; r2[tid] += r2[tid + off]; }
        __syncthreads();
    }
    if (tid == 0) {
        sv[0] = fmaxf(r1[0] * (1.f / 786432.f), 1e-5f);
        sv[1] = fmaxf(r2[0] * (1.f / 786432.f), 1e-5f);
    }
}

// ---------------------------------------------------------------------------
__global__ __launch_bounds__(256)
void quantize_both(const float* __restrict__ w1, const float* __restrict__ w2,
                   const float* __restrict__ sv,
                   u16* __restrict__ wq1, u16* __restrict__ wq2) {
    const int idx = blockIdx.x * 256 + threadIdx.x;   // [0, 786432)
    const float s1 = sv[0], s2 = sv[1];
    const int o   = idx / 1536;
    const int rem = idx - o * 1536;
    const int i   = rem / 3;
    const int k   = rem - i * 3;
    const int dst = k * (CCH * CCH) + o * CCH + i;
    float q1 = fmaxf(-1.f, fminf(1.f, rintf(w1[idx] / s1)));
    float q2 = fmaxf(-1.f, fminf(1.f, rintf(w2[idx] / s2)));
    wq1[dst] = f2bf(q1);
    wq2[dst] = f2bf(q2);
}

__global__ __launch_bounds__(256)
void zero_pads(u16* __restrict__ h, u16* __restrict__ h1) {
    const int idx = blockIdx.x * 256 + threadIdx.x;   // [0, 16384)
    const int b = idx >> 10;
    const int r = (idx >> 9) & 1;
    const int i = idx & 511;
    const size_t off = ((size_t)b * LPAD + (r ? (LPAD - 1) : 0)) * CCH + i;
    h[off] = 0;
    h1[off] = 0;
}

// ---------------------------------------------------------------------------
__global__ __launch_bounds__(256)
void rms_silu_transpose(const float* __restrict__ x, const float* __restrict__ g,
                        u16* __restrict__ h_t) {
    __shared__ u16   xt[CCH][33];
    __shared__ float red[8][32];
    __shared__ float rinv[32];
    const int tid = threadIdx.x;
    const int bb  = blockIdx.x >> 7;
    const int l0  = (blockIdx.x & 127) << 5;

    const size_t xbase = (size_t)bb * CCH * LEN + l0;
    {
        const int i_hi = tid >> 3;
        const int l4   = (tid & 7) << 2;
        #pragma unroll
        for (int it = 0; it < 16; ++it) {
            const int i = it * 32 + i_hi;
            const float4 v = *(const float4*)&x[xbase + (size_t)i * LEN + l4];
            xt[i][l4 + 0] = f2bf(v.x);
            xt[i][l4 + 1] = f2bf(v.y);
            xt[i][l4 + 2] = f2bf(v.z);
            xt[i][l4 + 3] = f2bf(v.w);
        }
    }
    __syncthreads();
    {
        const int l = tid & 31, seg = tid >> 5;
        const int ibeg = seg * 64;
        float ss = 0.f;
        #pragma unroll 8
        for (int i = ibeg; i < ibeg + 64; ++i) {
            const float v = bf2f(xt[i][l]);
            ss += v * v;
        }
        red[seg][l] = ss;
    }
    __syncthreads();
    if (tid < 32) {
        float tot = 0.f;
        #pragma unroll
        for (int k2 = 0; k2 < 8; ++k2) tot += red[k2][tid];
        rinv[tid] = rsqrtf(tot * (1.f / 512.f) + 1e-6f);
    }
    __syncthreads();
    {
        const int l  = tid >> 3;
        const int i0 = (tid & 7) << 6;
        const float ri = rinv[l];
        const size_t ob = ((size_t)bb * LPAD + l0 + l + 1) * CCH + i0;
        for (int ii = 0; ii < 64; ii += 8) {
            u16x8 ov;
            #pragma unroll
            for (int jj = 0; jj < 8; ++jj) {
                const int i = i0 + ii + jj;
                float v = bf2f(xt[i][l]) * ri * g[i];
                ov[jj] = f2bf(silu_f(v));
            }
            *(u16x8*)&h_t[ob + ii] = ov;
        }
    }
}

// ---------------------------------------------------------------------------
// Conv-as-GEMM.  256x256 block tile, BK=32, 48 K-steps.  512 threads =
// 8 waves (2M x 4N), per-wave 128x64 (8x4 frags, 12 ds_read per 32 MFMA
// -> read:MFMA cycle ratio 0.23).  TRIPLE-buffered LDS (3 x 32 KiB) with
// prefetch depth 2 + counted vmcnt(4): each tile's loads get a full step
// of slack before being waited on.  Paired-row LDS layout: rows 2L,2L+1
// packed into one 128B line; chunk' = ((row&1)*4 | q) ^ (line&7)
// -> exactly 2 lanes per bank-quad per ds_read_b128 (free).  gload_lds
// stays linear; inverse permutation folded into per-thread SOURCE addrs.
// setprio kept (R11: removing it cost 28%).  T1 XCD chunking.
template<int EPI>
__global__ __launch_bounds__(512)
void conv_gemm12(const u16* __restrict__ Bsrc, const u16* __restrict__ Wq,
                 const float* __restrict__ sptr, const float* __restrict__ bias,
                 const float* __restrict__ resid, u16* __restrict__ outb,
                 float* __restrict__ outf) {
    extern __shared__ u16 lds[];          // 131072 B requested (k-loop uses 96KB)
    const int tid  = threadIdx.x;
    const int lane = tid & 63;
    const int wave = tid >> 6;
    const int wm = wave >> 2;             // 0..1  (M half, 128 rows)
    const int wn = wave & 3;              // 0..3  (N quarter, 64 cols)

    // T1: bijective XCD chunking (512 = 8 x 64); mt-pairs share a B-panel.
    const int wgid = (blockIdx.x & 7) * 64 + (blockIdx.x >> 3);
    const int mt = wgid & 1;
    const int nt = wgid >> 1;
    const int o0 = mt << 8;
    const int bb = nt >> 4;
    const int l0 = (nt & 15) << 8;

    // ---- staging geometry: invert the paired-row permutation per thread ----
    // slot s (16B units): line = s>>3, chunk' = s&7; val = chunk' ^ (line&7);
    // row = 2*line + (val>>2); colchunk = val&3.
    int rowj[2], coffj[2];
    #pragma unroll
    for (int j = 0; j < 2; ++j) {
        const int s = tid + j * 512;
        const int line = s >> 3;
        const int val  = (s & 7) ^ (line & 7);
        rowj[j]  = 2 * line + (val >> 2);
        coffj[j] = (val & 3) << 3;
    }
    const u16* aS0 = Wq + (size_t)(o0 + rowj[0]) * CCH + coffj[0];
    const u16* aS1 = Wq + (size_t)(o0 + rowj[1]) * CCH + coffj[1];
    const u16* bS0 = Bsrc + ((size_t)bb * LPAD + l0 + rowj[0]) * CCH + coffj[0];
    const u16* bS1 = Bsrc + ((size_t)bb * LPAD + l0 + rowj[1]) * CCH + coffj[1];

    // stage K-step (ks2, i02) into buffer pb: 4 async16 per thread
    auto stage_full = [&](int pb, int ks2, int i02) {
        const int aoff = ks2 * (CCH * CCH) + i02;
        const int boff = ks2 * CCH + i02;
        u16* const base = &lds[pb * 16384];
        async16(aS0 + aoff, base + tid * 8);
        async16(aS1 + aoff, base + 4096 + tid * 8);
        async16(bS0 + boff, base + 8192 + tid * 8);
        async16(bS1 + boff, base + 12288 + tid * 8);
    };

    // ---- read geometry (paired-row layout) ----
    const int q = lane >> 4;                            // k-chunk 0..3
    const int halfl = (lane & 15) >> 1;                 // line offset 0..7
    const int chunkp = (((lane & 1) << 2) | q) ^ halfl; // swizzled chunk
    const int aBase = wm * 4096 + halfl * 64 + chunkp * 8;          // + m*512
    const int bBase = 8192 + wn * 2048 + halfl * 64 + chunkp * 8;   // + n*512

    f32x4 acc[8][4];
    #pragma unroll
    for (int m = 0; m < 8; ++m)
        #pragma unroll
        for (int n = 0; n < 4; ++n)
            acc[m][n] = (f32x4){0.f, 0.f, 0.f, 0.f};

    // prologue: t0 -> buf0, t1 -> buf1; wait t0 (t1's 4 stay in flight)
    stage_full(0, 0, 0);
    stage_full(1, 1, 0);
    WAIT_VM(4);
    HWBAR();

    int pb = 0;
    int ks2 = 2, i02 = 0;                 // params of tile t+2
    for (int t = 0; t < 48; ++t) {
        if (t < 46) {
            int nb = pb + 2; if (nb >= 3) nb -= 3;
            stage_full(nb, ks2, i02);
            ++ks2; if (ks2 == 3) { ks2 = 0; i02 += 32; }
        }
        const int cb = pb * 16384;
        bf16x8 ar[8], br[4];
        #pragma unroll
        for (int m = 0; m < 8; ++m)
            ar[m] = *(const bf16x8*)&lds[cb + aBase + m * 512];
        #pragma unroll
        for (int n = 0; n < 4; ++n)
            br[n] = *(const bf16x8*)&lds[cb + bBase + n * 512];
        __builtin_amdgcn_s_setprio(1);
        #pragma unroll
        for (int m = 0; m < 8; ++m)
            #pragma unroll
            for (int n = 0; n < 4; ++n)
                acc[m][n] = __builtin_amdgcn_mfma_f32_16x16x32_bf16(
                    ar[m], br[n], acc[m][n], 0, 0, 0);
        __builtin_amdgcn_s_setprio(0);
        WAIT_LGKM0();                     // buf[pb] reads retired (WAR safety)
        if (t < 46) { WAIT_VM(4); }       // tile t+1 landed (1 step of slack)
        else if (t == 46) { WAIT_VM(0); } // last tile drained
        HWBAR();
        ++pb; if (pb == 3) pb = 0;
    }

    // epilogue
    const float sc = sptr[0];

    if (EPI == 1) {
        // silu(sc*acc+bias) -> LDS [l_loc 0..255][o_loc 0..255] bf16 swizzled
        // (row pitch 512B), then coalesced 16B stores.
        #pragma unroll
        for (int m = 0; m < 8; ++m) {
            const int o_loc = wm * 128 + m * 16 + ((lane >> 4) << 2);
            const int ob = o0 + o_loc;
            const float b0 = bias[ob + 0], b1 = bias[ob + 1];
            const float b2 = bias[ob + 2], b3 = bias[ob + 3];
            #pragma unroll
            for (int n = 0; n < 4; ++n) {
                const int l_loc = wn * 64 + n * 16 + (lane & 15);
                const f32x4 a = acc[m][n];
                u16x4 ov;
                ov[0] = f2bf(silu_f(sc * a[0] + b0));
                ov[1] = f2bf(silu_f(sc * a[1] + b1));
                ov[2] = f2bf(silu_f(sc * a[2] + b2));
                ov[3] = f2bf(silu_f(sc * a[3] + b3));
                char* p = (char*)lds + l_loc * 512 +
                          (((unsigned)(o_loc << 1)) ^ ((l_loc & 7) << 4));
                *(u16x4*)p = ov;
            }
        }
        __syncthreads();
        const int row  = tid >> 1;           // 0..255
        const int half = tid & 1;            // 0 or 1 (128 u16 each)
        u16* gdst = outb + ((size_t)bb * LPAD + l0 + row + 1) * CCH + o0 + half * 128;
        char* srp = (char*)lds + row * 512;
        const int swz2 = (row & 7) << 4;
        #pragma unroll
        for (int c = 0; c < 16; ++c) {
            const uint4 v = *(const uint4*)(srp + ((half * 256 + c * 16) ^ swz2));
            *(uint4*)(gdst + c * 8) = v;
        }
    } else {
        const int lbase = l0 + wn * 64 + (lane & 15);
        const int obase = o0 + wm * 128 + ((lane >> 4) << 2);
        #pragma unroll
        for (int m = 0; m < 8; ++m) {
            const int ob = obase + m * 16;
            #pragma unroll
            for (int n = 0; n < 4; ++n) {
                const int l = lbase + n * 16;
                const f32x4 a = acc[m][n];
                #pragma unroll
                for (int jj = 0; jj < 4; ++jj) {
                    const size_t idx = ((size_t)bb * CCH + (ob + jj)) * LEN + l;
                    outf[idx] = sc * a[jj] + bias[ob + jj] + resid[idx];
                }
            }
        }
    }
}

// ---------------------------------------------------------------------------
extern "C" void kernel_launch(void* const* d_in, const int* in_sizes, int n_in,
                              void* d_out, int out_size, void* d_ws, size_t ws_size,
                              hipStream_t stream) {
    const float* x  = (const float*)d_in[0];
    const float* w1 = (const float*)d_in[1];
    const float* b1 = (const float*)d_in[2];
    const float* w2 = (const float*)d_in[3];
    const float* b2 = (const float*)d_in[4];
    const float* g  = (const float*)d_in[5];
    float* out = (float*)d_out;

    char* ws = (char*)d_ws;
    float* sv   = (float*)ws;
    float* part = (float*)(ws + 256);
    u16* wq1   = (u16*)(ws + 4096);
    u16* wq2   = (u16*)(ws + 4096 + 1572864);
    u16* h_t   = (u16*)(ws + 4096 + 2 * 1572864);                 // [16][4098][512] bf16
    u16* h1_t  = (u16*)(ws + 4096 + 2 * 1572864 + 67141632);      // [16][4098][512] bf16

    hipFuncSetAttribute((const void*)conv_gemm12<1>,
                        hipFuncAttributeMaxDynamicSharedMemorySize, 131072);
    hipFuncSetAttribute((const void*)conv_gemm12<2>,
                        hipFuncAttributeMaxDynamicSharedMemorySize, 131072);

    absmean_partial<<<dim3(256), dim3(256), 0, stream>>>(w1, w2, part);
    finalize_scale<<<dim3(1), dim3(256), 0, stream>>>(part, sv);
    quantize_both<<<dim3(3072), dim3(256), 0, stream>>>(w1, w2, sv, wq1, wq2);
    zero_pads<<<dim3(64), dim3(256), 0, stream>>>(h_t, h1_t);
    rms_silu_transpose<<<dim3(2048), dim3(256), 0, stream>>>(x, g, h_t);
    conv_gemm12<1><<<dim3(512), dim3(512), 131072, stream>>>(h_t, wq1, sv, b1,
                                                             nullptr, h1_t, nullptr);
    conv_gemm12<2><<<dim3(512), dim3(512), 131072, stream>>>(h1_t, wq2, sv + 1, b2,
                                                             x, nullptr, out);
}